// Round 1
// baseline (485.909 us; speedup 1.0000x reference)
//
#include <hip/hip_runtime.h>
#include <hip/hip_bf16.h>

// Problem constants
#define NB     32
#define CIN    256
#define LIN    4096
#define COUT   256
#define KW     9
#define NGRP   4
#define CDIM   128
#define CPG    64          // channels per group (both in and out)
#define LT     256         // l-tile per pipeline stage
#define NROWS  264         // LT + 2*PAD halo rows
#define RP     68          // LDS row stride in bf16 elements: 136 B (8B-aligned b64, spreads banks on reads)
#define TPB    2           // tiles per block (pipelined)
#define WF_ELEMS (4*4*9*2*64*8)   // g * co16 * k * chunk * lane * j = 294912

typedef __attribute__((ext_vector_type(8))) short short8;    // 8 bf16 = 4 VGPRs (MFMA operand)
typedef __attribute__((ext_vector_type(4))) short short4v;
typedef __attribute__((ext_vector_type(4))) float float4v;
typedef __attribute__((ext_vector_type(4))) unsigned short ushort4v;

// ---- Pack weights (fp32, [co][ci][k]) into MFMA A-fragment-linear bf16 order ----
// wF[((((g*4+co16)*9+k)*2+chunk)*64+lane)*8 + j] = w[co= g*64+co16*16+(lane&15)][ci= chunk*32+(lane>>4)*8+j][k]
__global__ void pack_weights(const float* __restrict__ w, __hip_bfloat16* __restrict__ wF) {
    int tid = blockIdx.x * blockDim.x + threadIdx.x;
    if (tid >= WF_ELEMS) return;
    int j    = tid & 7;
    int lane = (tid >> 3) & 63;
    int rest = tid >> 9;
    int chunk = rest & 1;  rest >>= 1;
    int k     = rest % 9;  rest /= 9;
    int co16  = rest & 3;
    int g     = rest >> 2;
    int co = g * CPG + co16 * 16 + (lane & 15);
    int ci = chunk * 32 + (lane >> 4) * 8 + j;
    wF[tid] = __float2bfloat16(w[(co * CPG + ci) * KW + k]);
}

// ---- ctx[n][co] = c[n] . c_weight[co] + bias[co] : one wave per output, coalesced ----
__global__ __launch_bounds__(256) void ctx_kernel(const float* __restrict__ c,
                                                  const float* __restrict__ cw,
                                                  const float* __restrict__ bias,
                                                  float* __restrict__ ctxb) {
    int gw   = (blockIdx.x * 256 + threadIdx.x) >> 6;   // wave id: [0, 32*256)
    int lane = threadIdx.x & 63;
    int n  = gw >> 8;
    int co = gw & 255;
    float s = c[n * CDIM + lane]      * cw[co * CDIM + lane]
            + c[n * CDIM + 64 + lane] * cw[co * CDIM + 64 + lane];
    #pragma unroll
    for (int off = 32; off; off >>= 1) s += __shfl_down(s, off);
    if (lane == 0) ctxb[gw] = s + bias[co];
}

// ---- Main: implicit-GEMM grouped conv via bf16 MFMA, ci-chunk software pipeline ----
// Each block owns TPB=2 adjacent l-tiles of 256. The 64 input channels split into two
// 32-ci chunks living in DISJOINT LDS columns, so staging chunk c+1 overlaps computing
// chunk c with no extra LDS. Loads for the next chunk are always in flight during MFMA,
// keeping HBM issue near-continuous (the baseline's stage->barrier->compute convoy
// capped BW at 2.36/6.3 TB/s).
__global__ __launch_bounds__(256, 2) void conv_mfma(
    const float* __restrict__ x, const __hip_bfloat16* __restrict__ wF,
    const float* __restrict__ ctxb, float* __restrict__ out)
{
    __shared__ unsigned short sx[NROWS * RP];   // [row][ci], row = l_local (l = l0-4+row), 35,904 B
    __shared__ float sctx[CPG];

    const int bx = blockIdx.x;          // 1024 blocks = n(32) * g(4) * pair(8)
    const int pb = bx & 7;
    const int g  = (bx >> 3) & 3;
    const int n  = bx >> 5;
    const int t0 = pb * TPB;            // global tile index base, tiles t0..t0+TPB-1 (of 16)
    const int tid = threadIdx.x;
    const int lane = tid & 63;
    const int wv   = tid >> 6;

    if (tid < CPG) sctx[tid] = ctxb[n * COUT + g * CPG + tid];

    const float* xb = x + ((size_t)(n * CIN + g * CPG)) * LIN;

    // Staging registers: two ping-pong sets (one chunk each) + halo regs (tid<16 only).
    float4v rA[2][4], rB[2][4], rhA[4], rhB[4];

    // ---- Issue global loads for chunk c of tile tg into regs (coalesced float4, lanes sweep l) ----
    auto stage_load = [&](int c, int tg, float4v (&rm)[2][4], float4v (&rh)[4]) {
        const int l0 = tg * LT;
        #pragma unroll
        for (int it = 0; it < 2; ++it) {
            int cq = (lane >> 4) + 4 * it;              // ci-quad within chunk: 0..7
            int q4 = 1 + (lane & 15) + 16 * wv;         // l-quad 1..64 -> rows 4..259, in-bounds
            int lg = l0 - 4 + 4 * q4;
            #pragma unroll
            for (int j = 0; j < 4; ++j)
                rm[it][j] = *(const float4v*)(xb + (size_t)(32 * c + 4 * cq + j) * LIN + lg);
        }
        if (tid < 16) {                                  // halo rows 0..3 / 260..263
            bool head = tid < 8;
            int q4 = head ? 0 : 65;
            int cq = tid & 7;
            int lg = l0 - 4 + 4 * q4;
            bool ok = head ? (tg > 0) : (tg < 15);
            #pragma unroll
            for (int j = 0; j < 4; ++j)
                rh[j] = ok ? *(const float4v*)(xb + (size_t)(32 * c + 4 * cq + j) * LIN + lg)
                           : (float4v){0.f, 0.f, 0.f, 0.f};
        }
    };

    // ---- Convert + in-register 4x4 transpose + LDS write for chunk c (cols 32c..32c+31) ----
    auto stage_write = [&](int c, float4v (&rm)[2][4], float4v (&rh)[4]) {
        #pragma unroll
        for (int it = 0; it < 2; ++it) {
            int cq = (lane >> 4) + 4 * it;
            int q4 = 1 + (lane & 15) + 16 * wv;
            int row = 4 * q4;
            int colu = 4 * (8 * c + cq);
            #pragma unroll
            for (int d = 0; d < 4; ++d) {
                ushort4v p;
                #pragma unroll
                for (int j = 0; j < 4; ++j)
                    p[j] = __builtin_bit_cast(unsigned short, __float2bfloat16(rm[it][j][d]));
                *(ushort4v*)(&sx[(row + d) * RP + colu]) = p;
            }
        }
        if (tid < 16) {
            int q4 = (tid < 8) ? 0 : 65;
            int cq = tid & 7;
            int row = 4 * q4;                 // 0 or 260
            int colu = 4 * (8 * c + cq);
            #pragma unroll
            for (int d = 0; d < 4; ++d) {
                ushort4v p;
                #pragma unroll
                for (int j = 0; j < 4; ++j)
                    p[j] = __builtin_bit_cast(unsigned short, __float2bfloat16(rh[j][d]));
                *(ushort4v*)(&sx[(row + d) * RP + colu]) = p;
            }
        }
    };

    const int r  = lane & 15;
    const int q  = lane >> 4;
    const int wl = wv * 64;
    const short8* wFp = (const short8*)wF;

    float4v acc[4][4];              // [co16][l16]
    #pragma unroll
    for (int a = 0; a < 4; ++a)
        #pragma unroll
        for (int b = 0; b < 4; ++b)
            acc[a][b] = (float4v){0.f, 0.f, 0.f, 0.f};

    // ---- MFMA k-loop over one 32-ci chunk (reads LDS cols 32c..32c+31 only) ----
    auto compute_chunk = [&](int c) {
        #pragma unroll
        for (int k = 0; k < KW; ++k) {
            short8 bfrag[4];
            #pragma unroll
            for (int l16 = 0; l16 < 4; ++l16) {
                int row = wl + l16 * 16 + r + k;            // out-l + k shift
                int base = row * RP + c * 32 + q * 8;
                short4v lo = *(const short4v*)(&sx[base]);
                short4v hi = *(const short4v*)(&sx[base + 4]);
                bfrag[l16] = __builtin_shufflevector(lo, hi, 0, 1, 2, 3, 4, 5, 6, 7);
            }
            #pragma unroll
            for (int co16 = 0; co16 < 4; ++co16) {
                short8 af = wFp[(((g * 4 + co16) * 9 + k) * 2 + c) * 64 + lane];
                #pragma unroll
                for (int l16 = 0; l16 < 4; ++l16)
                    acc[co16][l16] = __builtin_amdgcn_mfma_f32_16x16x32_bf16(
                        af, bfrag[l16], acc[co16][l16], 0, 0, 0);
            }
        }
    };

    // ---- Prologue: fill chunk0, put chunk1 in flight ----
    stage_load(0, t0, rA, rhA);
    stage_load(1, t0, rB, rhB);
    stage_write(0, rA, rhA);
    __syncthreads();

    // ---- Pipelined tile loop. Invariant at loop head: cols0 hold tile tt chunk0 (all
    // waves synced), rB holds tile tt chunk1 (loads in flight). ----
    #pragma unroll 1
    for (int tt = 0; tt < TPB; ++tt) {
        const int tg = t0 + tt;

        compute_chunk(0);                                // reads cols0  [chunk1 loads in flight]
        stage_write(1, rB, rhB);                         // cols1: no reader until next barrier
        if (tt + 1 < TPB) stage_load(0, tg + 1, rA, rhA);// next tile chunk0 -> in flight over C1
        __syncthreads();                                 // cols1 visible; all waves done with cols0

        compute_chunk(1);                                // reads cols1  [next chunk0 in flight]

        // Epilogue for this tile: D layout col = lane&15 (l), row = q*4+reg (co).
        {
            float* ob = out + ((size_t)(n * COUT + g * CPG)) * LIN + tg * LT + wl;
            #pragma unroll
            for (int co16 = 0; co16 < 4; ++co16) {
                #pragma unroll
                for (int rg = 0; rg < 4; ++rg) {
                    int co_l = co16 * 16 + q * 4 + rg;
                    float add = sctx[co_l];
                    #pragma unroll
                    for (int l16 = 0; l16 < 4; ++l16)
                        ob[(size_t)co_l * LIN + l16 * 16 + r] = acc[co16][l16][rg] + add;
                }
            }
            #pragma unroll
            for (int a = 0; a < 4; ++a)
                #pragma unroll
                for (int b = 0; b < 4; ++b)
                    acc[a][b] = (float4v){0.f, 0.f, 0.f, 0.f};
        }

        if (tt + 1 < TPB) {
            stage_write(0, rA, rhA);                     // overwrite cols0: safe, all waves passed
                                                         // the mid barrier (done reading cols0)
            stage_load(1, tg + 1, rB, rhB);              // next tile chunk1 -> in flight
        }
        __syncthreads();                                 // cols0(next) visible; all done with cols1
    }
}

extern "C" void kernel_launch(void* const* d_in, const int* in_sizes, int n_in,
                              void* d_out, int out_size, void* d_ws, size_t ws_size,
                              hipStream_t stream) {
    const float* x    = (const float*)d_in[0];   // (32, 256, 4096)
    const float* c    = (const float*)d_in[1];   // (32, 128)
    const float* w    = (const float*)d_in[2];   // (256, 64, 9)
    const float* cw   = (const float*)d_in[3];   // (256, 128)
    const float* bias = (const float*)d_in[4];   // (256,)
    float* out = (float*)d_out;                  // (32, 256, 4096)

    __hip_bfloat16* wF = (__hip_bfloat16*)d_ws;                       // 589,824 B
    float* ctxb = (float*)((char*)d_ws + (size_t)WF_ELEMS * 2);       // 32,768 B

    pack_weights<<<(WF_ELEMS + 255) / 256, 256, 0, stream>>>(w, wF);
    ctx_kernel<<<(NB * COUT * 64) / 256, 256, 0, stream>>>(c, cw, bias, ctxb);
    conv_mfma<<<NB * NGRP * (LIN / LT / TPB), 256, 0, stream>>>(x, wF, ctxb, out);
}

// Round 2
// 427.372 us; speedup vs baseline: 1.1370x; 1.1370x over previous
//
#include <hip/hip_runtime.h>
#include <hip/hip_bf16.h>

// Problem constants
#define NB     32
#define CIN    256
#define LIN    4096
#define COUT   256
#define KW     9
#define NGRP   4
#define CDIM   128
#define CPG    64          // channels per group (both in and out)
#define LT     256         // l-tile per pipeline stage
#define NROWS  264         // LT + 2*PAD halo rows
#define RP     68          // LDS row stride in bf16 elements: 136 B (8B-aligned b64, spreads banks on reads)
#define TPB    2           // tiles per block (chunk-granular pipeline)
#define WF_ELEMS (4*4*9*2*64*8)   // g * co16 * k * chunk * lane * j = 294912

typedef __attribute__((ext_vector_type(8))) short short8;    // 8 bf16 = 4 VGPRs (MFMA operand)
typedef __attribute__((ext_vector_type(4))) short short4v;
typedef __attribute__((ext_vector_type(4))) float float4v;
typedef __attribute__((ext_vector_type(4))) unsigned short ushort4v;

// ---- Pack weights (fp32, [co][ci][k]) into MFMA A-fragment-linear bf16 order ----
// wF[((((g*4+co16)*9+k)*2+chunk)*64+lane)*8 + j] = w[co= g*64+co16*16+(lane&15)][ci= chunk*32+(lane>>4)*8+j][k]
__global__ void pack_weights(const float* __restrict__ w, __hip_bfloat16* __restrict__ wF) {
    int tid = blockIdx.x * blockDim.x + threadIdx.x;
    if (tid >= WF_ELEMS) return;
    int j    = tid & 7;
    int lane = (tid >> 3) & 63;
    int rest = tid >> 9;
    int chunk = rest & 1;  rest >>= 1;
    int k     = rest % 9;  rest /= 9;
    int co16  = rest & 3;
    int g     = rest >> 2;
    int co = g * CPG + co16 * 16 + (lane & 15);
    int ci = chunk * 32 + (lane >> 4) * 8 + j;
    wF[tid] = __float2bfloat16(w[(co * CPG + ci) * KW + k]);
}

// ---- ctx[n][co] = c[n] . c_weight[co] + bias[co] : one wave per output, coalesced ----
__global__ __launch_bounds__(256) void ctx_kernel(const float* __restrict__ c,
                                                  const float* __restrict__ cw,
                                                  const float* __restrict__ bias,
                                                  float* __restrict__ ctxb) {
    int gw   = (blockIdx.x * 256 + threadIdx.x) >> 6;   // wave id: [0, 32*256)
    int lane = threadIdx.x & 63;
    int n  = gw >> 8;
    int co = gw & 255;
    float s = c[n * CDIM + lane]      * cw[co * CDIM + lane]
            + c[n * CDIM + 64 + lane] * cw[co * CDIM + 64 + lane];
    #pragma unroll
    for (int off = 32; off; off >>= 1) s += __shfl_down(s, off);
    if (lane == 0) ctxb[gw] = s + bias[co];
}

// ---- Main: implicit-GEMM grouped conv via bf16 MFMA, SINGLE-RAIL ci-chunk pipeline ----
// Round-1 lesson: a two-rail register pipeline spilled (hbm_bytes 2.4e8 -> 9.5e8 = scratch).
// This version uses ONE staging register set S (32 VGPR + 4 halo): write S->LDS, then
// immediately re-issue S for the next chunk, then compute. Since vmcnt drains in order
// (compute's weight loads force-drain x loads), prefetch distance beyond ~1 compute
// phase is unusable anyway; 1 phase (~700-900 cyc) ~ HBM latency, so the drain finds
// the loads mostly landed. Budget: ~85 arch VGPR + 64 acc <= 170 @ launch_bounds(256,3).
__global__ __launch_bounds__(256, 3) void conv_mfma(
    const float* __restrict__ x, const __hip_bfloat16* __restrict__ wF,
    const float* __restrict__ ctxb, float* __restrict__ out)
{
    __shared__ unsigned short sx[NROWS * RP];   // [row][ci], row = l_local (l = l0-4+row), 35,904 B
    __shared__ float sctx[CPG];

    const int bx = blockIdx.x;          // 1024 blocks = n(32) * g(4) * pair(8)
    const int pb = bx & 7;
    const int g  = (bx >> 3) & 3;
    const int n  = bx >> 5;
    const int t0 = pb * TPB;            // tiles t0..t0+TPB-1 (of 16)
    const int tid = threadIdx.x;
    const int lane = tid & 63;
    const int wv   = tid >> 6;

    if (tid < CPG) sctx[tid] = ctxb[n * COUT + g * CPG + tid];

    const float* xb = x + ((size_t)(n * CIN + g * CPG)) * LIN;

    // Single staging rail: 8 float4 (main rows) + 1 float4 (halo, tid<64 only).
    float4v S[8];
    float4v Sh;

    // staging geometry (fixed per thread)
    const int s_q4 = 1 + (lane & 15) + 16 * wv;   // l-quad 1..64 -> rows 4..259, in-bounds
    const int s_cq = lane >> 4;                   // base ci-quad 0..3 (+4 for it=1)
    const int h_q4 = (tid < 32) ? 0 : 65;         // halo: rows 0..3 / 260..263
    const int h_ci = tid & 31;                    // one ci per halo thread

    // ---- Issue global loads for chunk c of tile tg into S (coalesced float4, lanes sweep l) ----
    auto stage_load = [&](int c, int tg) {
        const int lg = tg * LT - 4 + 4 * s_q4;
        #pragma unroll
        for (int it = 0; it < 2; ++it)
            #pragma unroll
            for (int j = 0; j < 4; ++j)
                S[it * 4 + j] = *(const float4v*)(xb + (size_t)(32 * c + 4 * (s_cq + 4 * it) + j) * LIN + lg);
        if (tid < 64) {
            bool ok = (tid < 32) ? (tg > 0) : (tg < 15);
            const float* p = xb + (size_t)(32 * c + h_ci) * LIN + (tg * LT - 4 + 4 * h_q4);
            Sh = ok ? *(const float4v*)p : (float4v){0.f, 0.f, 0.f, 0.f};
        }
    };

    // ---- Convert + in-register 4x4 transpose + LDS write for chunk c (cols 32c..32c+31) ----
    auto stage_write = [&](int c) {
        #pragma unroll
        for (int it = 0; it < 2; ++it) {
            int colu = 32 * c + 4 * (s_cq + 4 * it);
            int row  = 4 * s_q4;
            #pragma unroll
            for (int d = 0; d < 4; ++d) {
                ushort4v p;
                #pragma unroll
                for (int j = 0; j < 4; ++j)
                    p[j] = __builtin_bit_cast(unsigned short, __float2bfloat16(S[it * 4 + j][d]));
                *(ushort4v*)(&sx[(row + d) * RP + colu]) = p;
            }
        }
        if (tid < 64) {
            int row = 4 * h_q4;                 // 0 or 260
            int col = 32 * c + h_ci;
            #pragma unroll
            for (int d = 0; d < 4; ++d)
                sx[(row + d) * RP + col] = __builtin_bit_cast(unsigned short, __float2bfloat16(Sh[d]));
        }
    };

    const int r  = lane & 15;
    const int q  = lane >> 4;
    const int wl = wv * 64;
    const short8* wFp = (const short8*)wF;

    float4v acc[4][4];              // [co16][l16]
    #pragma unroll
    for (int a = 0; a < 4; ++a)
        #pragma unroll
        for (int b = 0; b < 4; ++b)
            acc[a][b] = (float4v){0.f, 0.f, 0.f, 0.f};

    // ---- MFMA k-loop over one 32-ci chunk (reads LDS cols 32c..32c+31 only) ----
    auto compute_chunk = [&](int c) {
        #pragma unroll
        for (int k = 0; k < KW; ++k) {
            short8 bfrag[4];
            #pragma unroll
            for (int l16 = 0; l16 < 4; ++l16) {
                int row = wl + l16 * 16 + r + k;            // out-l + k shift
                int base = row * RP + c * 32 + q * 8;
                short4v lo = *(const short4v*)(&sx[base]);
                short4v hi = *(const short4v*)(&sx[base + 4]);
                bfrag[l16] = __builtin_shufflevector(lo, hi, 0, 1, 2, 3, 4, 5, 6, 7);
            }
            #pragma unroll
            for (int co16 = 0; co16 < 4; ++co16) {
                short8 af = wFp[(((g * 4 + co16) * 9 + k) * 2 + c) * 64 + lane];
                #pragma unroll
                for (int l16 = 0; l16 < 4; ++l16)
                    acc[co16][l16] = __builtin_amdgcn_mfma_f32_16x16x32_bf16(
                        af, bfrag[l16], acc[co16][l16], 0, 0, 0);
            }
        }
    };

    // ---- Prologue: fill cols0, put chunk1 in flight ----
    stage_load(0, t0);
    stage_write(0);                 // waits S (startup latency, once)
    stage_load(1, t0);              // chunk1 in flight across the barrier
    __syncthreads();

    // ---- Pipelined tile loop. Invariant at loop head: cols[0] = chunk0(tg) visible,
    // S in flight = chunk1(tg). Every compute phase has the next chunk's loads in flight. ----
    #pragma unroll
    for (int tt = 0; tt < TPB; ++tt) {
        const int tg = t0 + tt;

        compute_chunk(0);                        // reads cols0   [S=c1(tg) in flight]
        stage_write(1);                          // waitcnt S (had a full compute to land)
        if (tt + 1 < TPB) stage_load(0, tg + 1); // next tile chunk0 -> in flight
        __syncthreads();                         // cols1 visible; all waves done with cols0

        compute_chunk(1);                        // reads cols1   [S=c0(tg+1) in flight]

        // Epilogue: D layout col = lane&15 (l), row = q*4+reg (co). Add ctx+bias, store.
        {
            float* ob = out + ((size_t)(n * COUT + g * CPG)) * LIN + (size_t)tg * LT + wl;
            #pragma unroll
            for (int co16 = 0; co16 < 4; ++co16) {
                #pragma unroll
                for (int rg = 0; rg < 4; ++rg) {
                    int co_l = co16 * 16 + q * 4 + rg;
                    float add = sctx[co_l];
                    #pragma unroll
                    for (int l16 = 0; l16 < 4; ++l16)
                        ob[(size_t)co_l * LIN + l16 * 16 + r] = acc[co16][l16][rg] + add;
                }
            }
            #pragma unroll
            for (int a = 0; a < 4; ++a)
                #pragma unroll
                for (int b = 0; b < 4; ++b)
                    acc[a][b] = (float4v){0.f, 0.f, 0.f, 0.f};
        }

        if (tt + 1 < TPB) {
            stage_write(0);                      // overwrite cols0: all waves passed mid barrier
            stage_load(1, tg + 1);               // next tile chunk1 -> in flight
            __syncthreads();                     // cols0 visible; all done reading cols1
        }
    }
}

extern "C" void kernel_launch(void* const* d_in, const int* in_sizes, int n_in,
                              void* d_out, int out_size, void* d_ws, size_t ws_size,
                              hipStream_t stream) {
    const float* x    = (const float*)d_in[0];   // (32, 256, 4096)
    const float* c    = (const float*)d_in[1];   // (32, 128)
    const float* w    = (const float*)d_in[2];   // (256, 64, 9)
    const float* cw   = (const float*)d_in[3];   // (256, 128)
    const float* bias = (const float*)d_in[4];   // (256,)
    float* out = (float*)d_out;                  // (32, 256, 4096)

    __hip_bfloat16* wF = (__hip_bfloat16*)d_ws;                       // 589,824 B
    float* ctxb = (float*)((char*)d_ws + (size_t)WF_ELEMS * 2);       // 32,768 B

    pack_weights<<<(WF_ELEMS + 255) / 256, 256, 0, stream>>>(w, wF);
    ctx_kernel<<<(NB * COUT * 64) / 256, 256, 0, stream>>>(c, cw, bias, ctxb);
    conv_mfma<<<NB * NGRP * (LIN / LT / TPB), 256, 0, stream>>>(x, wF, ctxb, out);
}

// Round 3
// 276.519 us; speedup vs baseline: 1.7572x; 1.5455x over previous
//
#include <hip/hip_runtime.h>
#include <hip/hip_bf16.h>

// Problem constants
#define NB     32
#define CIN    256
#define LIN    4096
#define COUT   256
#define KW     9
#define NGRP   4
#define CDIM   128
#define CPG    64          // channels per group (both in and out)
#define LT     128         // l-tile per workgroup (halved vs round 0: occupancy over tile size)
#define NTILE  (LIN / LT)  // 32 tiles per (n,g)
#define NROWS  (LT + 8)    // 136: LT + 2*PAD halo rows
#define RP     68          // LDS row stride in bf16 elems: 136 B (b64-aligned, odd*34 dwords spreads banks)
#define WF_ELEMS (4*4*9*2*64*8)   // g * co16 * k * chunk * lane * j = 294912

typedef __attribute__((ext_vector_type(8))) short short8;    // 8 bf16 = 4 VGPRs (MFMA operand)
typedef __attribute__((ext_vector_type(4))) short short4v;
typedef __attribute__((ext_vector_type(4))) float float4v;
typedef __attribute__((ext_vector_type(4))) unsigned short ushort4v;

// ---- Pack weights (fp32, [co][ci][k]) into MFMA A-fragment-linear bf16 order ----
// wF[((((g*4+co16)*9+k)*2+chunk)*64+lane)*8 + j] = w[co= g*64+co16*16+(lane&15)][ci= chunk*32+(lane>>4)*8+j][k]
__global__ void pack_weights(const float* __restrict__ w, __hip_bfloat16* __restrict__ wF) {
    int tid = blockIdx.x * blockDim.x + threadIdx.x;
    if (tid >= WF_ELEMS) return;
    int j    = tid & 7;
    int lane = (tid >> 3) & 63;
    int rest = tid >> 9;
    int chunk = rest & 1;  rest >>= 1;
    int k     = rest % 9;  rest /= 9;
    int co16  = rest & 3;
    int g     = rest >> 2;
    int co = g * CPG + co16 * 16 + (lane & 15);
    int ci = chunk * 32 + (lane >> 4) * 8 + j;
    wF[tid] = __float2bfloat16(w[(co * CPG + ci) * KW + k]);
}

// ---- ctx[n][co] = c[n] . c_weight[co] + bias[co] : one wave per output, coalesced ----
__global__ __launch_bounds__(256) void ctx_kernel(const float* __restrict__ c,
                                                  const float* __restrict__ cw,
                                                  const float* __restrict__ bias,
                                                  float* __restrict__ ctxb) {
    int gw   = (blockIdx.x * 256 + threadIdx.x) >> 6;   // wave id: [0, 32*256)
    int lane = threadIdx.x & 63;
    int n  = gw >> 8;
    int co = gw & 255;
    float s = c[n * CDIM + lane]      * cw[co * CDIM + lane]
            + c[n * CDIM + 64 + lane] * cw[co * CDIM + 64 + lane];
    #pragma unroll
    for (int off = 32; off; off >>= 1) s += __shfl_down(s, off);
    if (lane == 0) ctxb[gw] = s + bias[co];
}

// ---- Main: implicit-GEMM grouped conv via bf16 MFMA ----
// Round 1/2 lesson: any staging registers live ACROSS the MFMA phase spill (hbm_bytes
// 2.4e8 -> 7-9.5e8 = scratch traffic); compute already needs 64 acc + ~50 arch VGPRs.
// So overlap comes from TLP instead: LT=128 halves LDS (18.75 KB) and acc (32 AGPR),
// fitting 5 blocks/CU at launch_bounds(256,5) with NO cross-phase registers. Phase-
// diverse blocks interleave one block's staging with another's MFMA (m114 mechanism),
// raising HBM issue density vs round 0's ~3.6-block convoy.
__global__ __launch_bounds__(256, 5) void conv_mfma(
    const float* __restrict__ x, const __hip_bfloat16* __restrict__ wF,
    const float* __restrict__ ctxb, float* __restrict__ out)
{
    __shared__ unsigned short sx[NROWS * RP];   // [row][ci], row = l_local (l = l0-4+row), 18,496 B
    __shared__ float sctx[CPG];

    const int bx = blockIdx.x;          // 4096 blocks = n(32) * g(4) * tile(32)
    const int t  = bx & 31;
    const int g  = (bx >> 5) & 3;
    const int n  = bx >> 7;
    const int l0 = t * LT;
    const int tid = threadIdx.x;
    const int lane = tid & 63;
    const int wv   = tid >> 6;

    if (tid < CPG) sctx[tid] = ctxb[n * COUT + g * CPG + tid];

    const float* xb = x + ((size_t)(n * CIN + g * CPG)) * LIN;

    // ---- Main staging: q4 (l-quad) = 1..32 -> rows 4..131, always in-bounds ----
    // Per wave-instr: 16 lanes sweep q4 (256B contiguous) x 4 ci rows -> coalesced.
    {
        int q4  = 1 + (lane & 15);
        int cqb = 4 * wv + (lane >> 4);   // ci-quad 0..15
        #pragma unroll
        for (int i = 0; i < 2; ++i, q4 += 16) {
            int lg = l0 - 4 + 4 * q4;
            float4v v[4];
            #pragma unroll
            for (int j = 0; j < 4; ++j)
                v[j] = *(const float4v*)(xb + (size_t)(4 * cqb + j) * LIN + lg);
            int row = 4 * q4;
            #pragma unroll
            for (int d = 0; d < 4; ++d) {
                ushort4v p;
                #pragma unroll
                for (int j = 0; j < 4; ++j)
                    p[j] = __builtin_bit_cast(unsigned short, __float2bfloat16(v[j][d]));
                *(ushort4v*)(&sx[(row + d) * RP + 4 * cqb]) = p;
            }
        }
    }
    // ---- Halo rows 0..3 (l0-4..l0-1) and 132..135 (l0+128..l0+131), block-uniform validity ----
    if (tid < 32) {
        int head = (tid < 16);
        int q4 = head ? 0 : (LT / 4 + 1);     // 0 or 33
        int cq = tid & 15;
        int lg = l0 - 4 + 4 * q4;
        bool ok = head ? (t > 0) : (t < NTILE - 1);
        float4v v[4];
        #pragma unroll
        for (int j = 0; j < 4; ++j)
            v[j] = ok ? *(const float4v*)(xb + (size_t)(4 * cq + j) * LIN + lg)
                      : (float4v){0.f, 0.f, 0.f, 0.f};
        int row = 4 * q4;                 // 0 or 132
        #pragma unroll
        for (int d = 0; d < 4; ++d) {
            ushort4v p;
            #pragma unroll
            for (int j = 0; j < 4; ++j)
                p[j] = __builtin_bit_cast(unsigned short, __float2bfloat16(v[j][d]));
            *(ushort4v*)(&sx[(row + d) * RP + 4 * cq]) = p;
        }
    }
    __syncthreads();

    const int r  = lane & 15;
    const int q  = lane >> 4;
    const int wl = wv * 32;               // 32 out-l per wave

    float4v acc[4][2];              // [co16][l16]
    #pragma unroll
    for (int a = 0; a < 4; ++a)
        #pragma unroll
        for (int b = 0; b < 2; ++b)
            acc[a][b] = (float4v){0.f, 0.f, 0.f, 0.f};

    const short8* wFp = (const short8*)wF;

    #pragma unroll
    for (int k = 0; k < KW; ++k) {
        #pragma unroll
        for (int chunk = 0; chunk < 2; ++chunk) {
            short8 bfrag[2];
            #pragma unroll
            for (int l16 = 0; l16 < 2; ++l16) {
                int row = wl + l16 * 16 + r + k;            // out-l + k shift, max 135
                int base = row * RP + chunk * 32 + q * 8;
                short4v lo = *(const short4v*)(&sx[base]);
                short4v hi = *(const short4v*)(&sx[base + 4]);
                bfrag[l16] = __builtin_shufflevector(lo, hi, 0, 1, 2, 3, 4, 5, 6, 7);
            }
            #pragma unroll
            for (int co16 = 0; co16 < 4; ++co16) {
                short8 af = wFp[(((g * 4 + co16) * 9 + k) * 2 + chunk) * 64 + lane];
                #pragma unroll
                for (int l16 = 0; l16 < 2; ++l16)
                    acc[co16][l16] = __builtin_amdgcn_mfma_f32_16x16x32_bf16(
                        af, bfrag[l16], acc[co16][l16], 0, 0, 0);
            }
        }
    }

    // Epilogue: D layout col = lane&15 (l), row = q*4+reg (co). Add ctx+bias, store coalesced.
    float* ob = out + ((size_t)(n * COUT + g * CPG)) * LIN + l0 + wl;
    #pragma unroll
    for (int co16 = 0; co16 < 4; ++co16) {
        #pragma unroll
        for (int reg = 0; reg < 4; ++reg) {
            int co_l = co16 * 16 + q * 4 + reg;
            float add = sctx[co_l];
            #pragma unroll
            for (int l16 = 0; l16 < 2; ++l16) {
                ob[(size_t)co_l * LIN + l16 * 16 + r] = acc[co16][l16][reg] + add;
            }
        }
    }
}

extern "C" void kernel_launch(void* const* d_in, const int* in_sizes, int n_in,
                              void* d_out, int out_size, void* d_ws, size_t ws_size,
                              hipStream_t stream) {
    const float* x    = (const float*)d_in[0];   // (32, 256, 4096)
    const float* c    = (const float*)d_in[1];   // (32, 128)
    const float* w    = (const float*)d_in[2];   // (256, 64, 9)
    const float* cw   = (const float*)d_in[3];   // (256, 128)
    const float* bias = (const float*)d_in[4];   // (256,)
    float* out = (float*)d_out;                  // (32, 256, 4096)

    __hip_bfloat16* wF = (__hip_bfloat16*)d_ws;                       // 589,824 B
    float* ctxb = (float*)((char*)d_ws + (size_t)WF_ELEMS * 2);       // 32,768 B

    pack_weights<<<(WF_ELEMS + 255) / 256, 256, 0, stream>>>(w, wF);
    ctx_kernel<<<(NB * COUT * 64) / 256, 256, 0, stream>>>(c, cw, bias, ctxb);
    conv_mfma<<<NB * NGRP * NTILE, 256, 0, stream>>>(x, wF, ctxb, out);
}

// Round 6
// 249.096 us; speedup vs baseline: 1.9507x; 1.1101x over previous
//
#include <hip/hip_runtime.h>
#include <hip/hip_bf16.h>

// Problem constants
#define NB     32
#define CIN    256
#define LIN    4096
#define COUT   256
#define KW     9
#define NGRP   4
#define CDIM   128
#define CPG    64          // channels per group (both in and out)
#define LT     128         // l-tile per workgroup
#define NTILE  (LIN / LT)  // 32 tiles per (n,g)
#define NROWS  (LT + 8)    // 136: LT + 2*PAD halo rows
#define RP     68          // LDS row stride in bf16 elems: 136 B (b64-aligned, spreads banks)
#define WF_ELEMS (4*4*9*2*64*8)   // g * co16 * k * chunk * lane * j = 294912

typedef __attribute__((ext_vector_type(8))) short short8;    // 8 bf16 = 4 VGPRs (MFMA operand)
typedef __attribute__((ext_vector_type(4))) short short4v;
typedef __attribute__((ext_vector_type(4))) float float4v;
typedef __attribute__((ext_vector_type(4))) unsigned short ushort4v;

// ---- Pack weights (fp32, [co][ci][k]) into MFMA A-fragment-linear bf16 order ----
// wF[((((g*4+co16)*9+k)*2+chunk)*64+lane)*8 + j] = w[co= g*64+co16*16+(lane&15)][ci= chunk*32+(lane>>4)*8+j][k]
__global__ void pack_weights(const float* __restrict__ w, __hip_bfloat16* __restrict__ wF) {
    int tid = blockIdx.x * blockDim.x + threadIdx.x;
    if (tid >= WF_ELEMS) return;
    int j    = tid & 7;
    int lane = (tid >> 3) & 63;
    int rest = tid >> 9;
    int chunk = rest & 1;  rest >>= 1;
    int k     = rest % 9;  rest /= 9;
    int co16  = rest & 3;
    int g     = rest >> 2;
    int co = g * CPG + co16 * 16 + (lane & 15);
    int ci = chunk * 32 + (lane >> 4) * 8 + j;
    wF[tid] = __float2bfloat16(w[(co * CPG + ci) * KW + k]);
}

// ---- ctx[n][co] = c[n] . c_weight[co] + bias[co] : one wave per output, coalesced ----
__global__ __launch_bounds__(256) void ctx_kernel(const float* __restrict__ c,
                                                  const float* __restrict__ cw,
                                                  const float* __restrict__ bias,
                                                  float* __restrict__ ctxb) {
    int gw   = (blockIdx.x * 256 + threadIdx.x) >> 6;   // wave id: [0, 32*256)
    int lane = threadIdx.x & 63;
    int n  = gw >> 8;
    int co = gw & 255;
    float s = c[n * CDIM + lane]      * cw[co * CDIM + lane]
            + c[n * CDIM + 64 + lane] * cw[co * CDIM + 64 + lane];
    #pragma unroll
    for (int off = 32; off; off >>= 1) s += __shfl_down(s, off);
    if (lane == 0) ctxb[gw] = s + bias[co];
}

// ---- Main: implicit-GEMM grouped conv via bf16 MFMA, register-resident weights ----
// Round 0/3 post-mortem: inner-loop wF global loads (L2) serialized every k-chunk
// iteration behind vmcnt(0) with zero prefetch depth (VGPR_Count=32!) -> all pipes
// <15% busy at BOTH 36% and 77% occupancy. Fix: each wave owns ONE co16 over the
// full l-tile, so its entire weight set (9k x 2chunk = 18 x short8 = 72 VGPR) is
// loaded ONCE per block and held in registers (statically indexed). The MFMA loop
// is then pure LDS+MFMA (compiler emits fine-grained lgkmcnt). Weight L2 traffic
// drops 4x. Staging issues all 9 x-loads before any convert (full MLP); staging
// regs die before weight+acc peak -> ~150 VGPR, no spill at launch_bounds(256,3).
__global__ __launch_bounds__(256, 3) void conv_mfma(
    const float* __restrict__ x, const __hip_bfloat16* __restrict__ wF,
    const float* __restrict__ ctxb, float* __restrict__ out)
{
    __shared__ unsigned short sx[NROWS * RP];   // [row][ci], row = l_local (l = l0-4+row), 18,496 B
    __shared__ float sctx[CPG];

    const int bx = blockIdx.x;          // 4096 blocks = n(32) * g(4) * tile(32)
    const int t  = bx & 31;
    const int g  = (bx >> 5) & 3;
    const int n  = bx >> 7;
    const int l0 = t * LT;
    const int tid = threadIdx.x;
    const int lane = tid & 63;
    const int wv   = tid >> 6;

    if (tid < CPG) sctx[tid] = ctxb[n * COUT + g * CPG + tid];

    // ---- Weight prefetch: wave wv owns co16 = wv. 18 fragments -> 72 VGPRs, issued
    // up front so they land under the staging/barrier phase. Static indexing only. ----
    const short8* wFp = (const short8*)wF;
    const short8* wbase = wFp + (size_t)((g * 4 + wv) * 9 * 2) * 64 + lane;
    short8 wreg[2 * KW];
    #pragma unroll
    for (int i = 0; i < 2 * KW; ++i) wreg[i] = wbase[(size_t)i * 64];

    const float* xb = x + ((size_t)(n * CIN + g * CPG)) * LIN;

    // ---- Stage x: issue ALL global loads first (MLP), then convert + 4x4 transpose + write ----
    const int q4  = 1 + (lane & 15);          // l-quad 1..16 (+16 for i=1) -> rows 4..131
    const int cqb = 4 * wv + (lane >> 4);     // ci-quad 0..15
    float4v v[8];
    #pragma unroll
    for (int i = 0; i < 2; ++i) {
        int lg = l0 - 4 + 4 * (q4 + 16 * i);
        #pragma unroll
        for (int j = 0; j < 4; ++j)
            v[i * 4 + j] = *(const float4v*)(xb + (size_t)(4 * cqb + j) * LIN + lg);
    }
    // halo rows 0..3 (l0-4..l0-1) and 132..135 (l0+128..l0+131), block-uniform validity
    float4v hv[4] = {{0.f,0.f,0.f,0.f},{0.f,0.f,0.f,0.f},{0.f,0.f,0.f,0.f},{0.f,0.f,0.f,0.f}};
    const int hq4 = (tid < 16) ? 0 : (LT / 4 + 1);   // 0 or 33
    const int hcq = tid & 15;
    if (tid < 32) {
        bool ok = (tid < 16) ? (t > 0) : (t < NTILE - 1);
        int lg = l0 - 4 + 4 * hq4;
        if (ok) {
            #pragma unroll
            for (int j = 0; j < 4; ++j)
                hv[j] = *(const float4v*)(xb + (size_t)(4 * hcq + j) * LIN + lg);
        }
    }
    #pragma unroll
    for (int i = 0; i < 2; ++i) {
        int row = 4 * (q4 + 16 * i);
        #pragma unroll
        for (int d = 0; d < 4; ++d) {
            ushort4v p;
            #pragma unroll
            for (int j = 0; j < 4; ++j)
                p[j] = __builtin_bit_cast(unsigned short, __float2bfloat16(v[i * 4 + j][d]));
            *(ushort4v*)(&sx[(row + d) * RP + 4 * cqb]) = p;
        }
    }
    if (tid < 32) {
        int row = 4 * hq4;                 // 0 or 132
        #pragma unroll
        for (int d = 0; d < 4; ++d) {
            ushort4v p;
            #pragma unroll
            for (int j = 0; j < 4; ++j)
                p[j] = __builtin_bit_cast(unsigned short, __float2bfloat16(hv[j][d]));
            *(ushort4v*)(&sx[(row + d) * RP + 4 * hcq]) = p;
        }
    }
    __syncthreads();

    const int r = lane & 15;
    const int q = lane >> 4;

    float4v acc[LT / 16];           // 8 l16 tiles, one co16 (= wv) each -> 32 regs
    #pragma unroll
    for (int b = 0; b < LT / 16; ++b)
        acc[b] = (float4v){0.f, 0.f, 0.f, 0.f};

    // ---- Pure LDS+MFMA inner loop: no global loads, no vmcnt stalls ----
    #pragma unroll
    for (int k = 0; k < KW; ++k) {
        #pragma unroll
        for (int ch = 0; ch < 2; ++ch) {
            short8 af = wreg[k * 2 + ch];
            #pragma unroll
            for (int l16 = 0; l16 < LT / 16; ++l16) {
                int row = l16 * 16 + r + k;            // out-l + k shift, max 135
                int base = row * RP + ch * 32 + q * 8;
                short4v lo = *(const short4v*)(&sx[base]);
                short4v hi = *(const short4v*)(&sx[base + 4]);
                short8 bf = __builtin_shufflevector(lo, hi, 0, 1, 2, 3, 4, 5, 6, 7);
                acc[l16] = __builtin_amdgcn_mfma_f32_16x16x32_bf16(af, bf, acc[l16], 0, 0, 0);
            }
        }
    }

    // Epilogue: D layout col = lane&15 (l), row = q*4+reg (co-within-16). Wave wv -> co16 = wv.
    float* ob = out + ((size_t)(n * COUT + g * CPG)) * LIN + l0;
    #pragma unroll
    for (int rg = 0; rg < 4; ++rg) {
        int co_l = wv * 16 + q * 4 + rg;
        float add = sctx[co_l];
        #pragma unroll
        for (int l16 = 0; l16 < LT / 16; ++l16)
            ob[(size_t)co_l * LIN + l16 * 16 + r] = acc[l16][rg] + add;
    }
}

extern "C" void kernel_launch(void* const* d_in, const int* in_sizes, int n_in,
                              void* d_out, int out_size, void* d_ws, size_t ws_size,
                              hipStream_t stream) {
    const float* x    = (const float*)d_in[0];   // (32, 256, 4096)
    const float* c    = (const float*)d_in[1];   // (32, 128)
    const float* w    = (const float*)d_in[2];   // (256, 64, 9)
    const float* cw   = (const float*)d_in[3];   // (256, 128)
    const float* bias = (const float*)d_in[4];   // (256,)
    float* out = (float*)d_out;                  // (32, 256, 4096)

    __hip_bfloat16* wF = (__hip_bfloat16*)d_ws;                       // 589,824 B
    float* ctxb = (float*)((char*)d_ws + (size_t)WF_ELEMS * 2);       // 32,768 B

    pack_weights<<<(WF_ELEMS + 255) / 256, 256, 0, stream>>>(w, wF);
    ctx_kernel<<<(NB * COUT * 64) / 256, 256, 0, stream>>>(c, cw, bias, ctxb);
    conv_mfma<<<NB * NGRP * NTILE, 256, 0, stream>>>(x, wF, ctxb, out);
}